// Round 3
// baseline (254.882 us; speedup 1.0000x reference)
//
#include <hip/hip_runtime.h>

constexpr int Bn = 4096;
constexpr int Dn = 256;
constexpr int Sn = 256;
constexpr int NITEMS = 100000;
constexpr int NBLK_SCAN = (NITEMS + 255) / 256;   // 391

// ---------------------------------------------------------------------------
// feat v3: f[4096][256] = uf_cat[4096][513] @ W^T[513][256] + bias
// 64x64 tile, 256 threads (16x16), 4x4 micro-tile, BK=32, k-major LDS,
// register-prefetch staging. grid = 64 * 4 = 256 blocks.
// ---------------------------------------------------------------------------
__global__ __launch_bounds__(256) void feat_v3(
    const float* __restrict__ uf, const float* __restrict__ priv,
    const float* __restrict__ W,  const float* __restrict__ bias,
    float* __restrict__ fout) {
  __shared__ float A_s[32][68];   // [k][m], +4 pad keeps float4 rows 16B-aligned
  __shared__ float B_s[32][68];   // [k][n]
  const int t  = threadIdx.x;
  const int m0 = (blockIdx.x >> 2) * 64;
  const int n0 = (blockIdx.x & 3) * 64;
  const int tx = t & 15, ty = t >> 4;

  float acc[4][4];
#pragma unroll
  for (int i = 0; i < 4; ++i)
#pragma unroll
    for (int j = 0; j < 4; ++j) acc[i][j] = 0.f;

  float ra[8], rb[8];
#pragma unroll
  for (int p = 0; p < 8; ++p) {
    const int e = t + p * 256, kk = e & 31, m = e >> 5;
    ra[p] = uf[(size_t)(m0 + m) * 512 + kk];
    rb[p] = W[(size_t)(n0 + m) * 513 + kk];
  }

  for (int c = 0; c < 16; ++c) {
#pragma unroll
    for (int p = 0; p < 8; ++p) {
      const int e = t + p * 256, kk = e & 31, m = e >> 5;
      A_s[kk][m] = ra[p];
      B_s[kk][m] = rb[p];
    }
    __syncthreads();
    if (c < 15) {
      const int k0 = (c + 1) * 32;
#pragma unroll
      for (int p = 0; p < 8; ++p) {
        const int e = t + p * 256, kk = e & 31, m = e >> 5;
        ra[p] = uf[(size_t)(m0 + m) * 512 + k0 + kk];
        rb[p] = W[(size_t)(n0 + m) * 513 + k0 + kk];
      }
    }
#pragma unroll
    for (int kk = 0; kk < 32; ++kk) {
      const float4 a4 = *(const float4*)&A_s[kk][ty * 4];
      const float4 b4 = *(const float4*)&B_s[kk][tx * 4];
      const float av[4] = {a4.x, a4.y, a4.z, a4.w};
      const float bv[4] = {b4.x, b4.y, b4.z, b4.w};
#pragma unroll
      for (int i = 0; i < 4; ++i)
#pragma unroll
        for (int j = 0; j < 4; ++j) acc[i][j] = fmaf(av[i], bv[j], acc[i][j]);
    }
    __syncthreads();
  }

  // tail k = 512: priv column
  float av[4], bv[4];
#pragma unroll
  for (int i = 0; i < 4; ++i) av[i] = priv[m0 + ty * 4 + i];
#pragma unroll
  for (int j = 0; j < 4; ++j) bv[j] = W[(size_t)(n0 + tx * 4 + j) * 513 + 512];
#pragma unroll
  for (int i = 0; i < 4; ++i)
#pragma unroll
    for (int j = 0; j < 4; ++j) acc[i][j] = fmaf(av[i], bv[j], acc[i][j]);

  const float4 bb = *(const float4*)&bias[n0 + tx * 4];
#pragma unroll
  for (int i = 0; i < 4; ++i) {
    float4 o;
    o.x = acc[i][0] + bb.x; o.y = acc[i][1] + bb.y;
    o.z = acc[i][2] + bb.z; o.w = acc[i][3] + bb.w;
    *(float4*)&fout[(size_t)(m0 + ty * 4 + i) * Dn + n0 + tx * 4] = o;
  }
}

// ---------------------------------------------------------------------------
// Index build: gather item ids per (b,s) + histogram
// ---------------------------------------------------------------------------
__global__ __launch_bounds__(256) void gather_hist(
    const int* __restrict__ need_replace, const int* __restrict__ user_sample_items,
    int* __restrict__ bsitems, int* __restrict__ cnt) {
  const int b = blockIdx.x, t = threadIdx.x;
  const int uid  = need_replace[b * 2];
  const int item = user_sample_items[(size_t)uid * Sn + t];
  bsitems[b * Sn + t] = item;
  atomicAdd(&cnt[item], 1);
}

__global__ __launch_bounds__(256) void scan_a(const int* __restrict__ cnt,
                                              int* __restrict__ offsets,
                                              int* __restrict__ blocksum) {
  __shared__ int s[256];
  const int tid = threadIdx.x;
  const int i = blockIdx.x * 256 + tid;
  const int v = (i < NITEMS) ? cnt[i] : 0;
  int x = v;
  s[tid] = x;
  __syncthreads();
  for (int d = 1; d < 256; d <<= 1) {
    const int add = (tid >= d) ? s[tid - d] : 0;
    __syncthreads();
    x += add;
    s[tid] = x;
    __syncthreads();
  }
  if (i < NITEMS) offsets[i] = x - v;      // block-local exclusive
  if (tid == 255) blocksum[blockIdx.x] = x;
}

__global__ __launch_bounds__(512) void scan_b(int* __restrict__ blocksum, int nblk) {
  __shared__ int s[512];
  const int tid = threadIdx.x;
  const int v = (tid < nblk) ? blocksum[tid] : 0;
  int x = v;
  s[tid] = x;
  __syncthreads();
  for (int d = 1; d < 512; d <<= 1) {
    const int add = (tid >= d) ? s[tid - d] : 0;
    __syncthreads();
    x += add;
    s[tid] = x;
    __syncthreads();
  }
  if (tid < nblk) blocksum[tid] = x - v;   // exclusive block offsets
}

__global__ __launch_bounds__(256) void scan_c(int* __restrict__ offsets,
                                              int* __restrict__ cursor,
                                              const int* __restrict__ blocksum) {
  const int i = blockIdx.x * 256 + threadIdx.x;
  if (i < NITEMS) {
    const int o = offsets[i] + blocksum[blockIdx.x];
    offsets[i] = o;
    cursor[i]  = o;
  }
}

__global__ __launch_bounds__(256) void scatter_kernel(
    const int* __restrict__ bsitems, int* __restrict__ cursor,
    int* __restrict__ consumers) {
  const int idx  = blockIdx.x * 256 + threadIdx.x;   // b*256+s
  const int item = bsitems[idx];
  const int pos  = atomicAdd(&cursor[item], 1);
  consumers[pos] = idx;
}

// ---------------------------------------------------------------------------
// fold helper (verified round 2): merges two value-families across lane bit m.
// ---------------------------------------------------------------------------
__device__ __forceinline__ float fold(float a, float b, int m, int lane) {
  const float keep = (lane & m) ? b : a;
  const float send = (lane & m) ? a : b;
  return keep + __shfl_xor(send, m, 64);
}

// ---------------------------------------------------------------------------
// score kernel: one wave per item. Item row streamed once (coalesced);
// f-rows gathered from the 4 MB L2-resident f table. 8 consumers per chunk:
// fold tree (32,16,8) + butterfly (4,2,1) -> lane 8j holds dot j.
// ---------------------------------------------------------------------------
__global__ __launch_bounds__(256) void score_kernel(
    const float* __restrict__ all_items, const float* __restrict__ f,
    const int* __restrict__ offsets, const int* __restrict__ cnt,
    const int* __restrict__ consumers, float* __restrict__ scores) {
  const int wv = threadIdx.x >> 6, lane = threadIdx.x & 63;
  const int item = blockIdx.x * 4 + wv;
  if (item >= NITEMS) return;
  const int nc = cnt[item];
  if (nc == 0) return;
  const int off = offsets[item];
  const float4 row = *(const float4*)&all_items[(size_t)item * Dn + lane * 4];
  const int j_of = lane >> 3;

  for (int c0 = 0; c0 < nc; c0 += 8) {
    const int rem = min(8, nc - c0);
    // this lane's store target (runtime j_of kept out of arrays -> no scratch)
    const int mycid = consumers[off + c0 + (j_of < rem ? j_of : 0)];
    float p[8];
#pragma unroll
    for (int j = 0; j < 8; ++j) {
      const int cid = consumers[off + c0 + (j < rem ? j : 0)];
      const float4 fv = *(const float4*)&f[(size_t)(cid >> 8) * Dn + lane * 4];
      const float d = fmaf(row.x, fv.x, fmaf(row.y, fv.y, fmaf(row.z, fv.z, row.w * fv.w)));
      p[j] = (j < rem) ? d : 0.f;
    }
    const float q0 = fold(p[0], p[4], 32, lane), q1 = fold(p[1], p[5], 32, lane);
    const float q2 = fold(p[2], p[6], 32, lane), q3 = fold(p[3], p[7], 32, lane);
    const float r0 = fold(q0, q2, 16, lane),     r1 = fold(q1, q3, 16, lane);
    float g = fold(r0, r1, 8, lane);
    g += __shfl_xor(g, 4, 64);
    g += __shfl_xor(g, 2, 64);
    g += __shfl_xor(g, 1, 64);
    if ((lane & 7) == 0 && j_of < rem) scores[mycid] = g;
  }
}

// ---------------------------------------------------------------------------
// finish: softmax over precomputed scores + weighted index + compacted pass-2
// ---------------------------------------------------------------------------
__global__ __launch_bounds__(256) void finish_kernel(
    const int* __restrict__ bsitems, const float* __restrict__ scores,
    const float* __restrict__ all_items,
    float* __restrict__ out_items, float* __restrict__ feat_out,
    float* __restrict__ out_scalars) {
  __shared__ float red_s[8];
  __shared__ int   sel_idx[Sn];
  __shared__ float sel_p[Sn];
  __shared__ int   warp_cnt[4];

  const int b = blockIdx.x, t = threadIdx.x;
  const int lane = t & 63, w = t >> 6;
  const int myitem = bsitems[b * Sn + t];
  const float v = scores[b * Sn + t];

  float m = v;
#pragma unroll
  for (int off = 32; off; off >>= 1) m = fmaxf(m, __shfl_xor(m, off, 64));
  if (lane == 0) red_s[w] = m;
  __syncthreads();
  m = fmaxf(fmaxf(red_s[0], red_s[1]), fmaxf(red_s[2], red_s[3]));

  const float e0 = expf(v - m);
  float ssum = e0;
#pragma unroll
  for (int off = 32; off; off >>= 1) ssum += __shfl_xor(ssum, off, 64);
  if (lane == 0) red_s[4 + w] = ssum;
  __syncthreads();
  const float tot = red_s[4] + red_s[5] + red_s[6] + red_s[7];
  const float p = e0 / tot;

  float ri = p * (float)myitem;
#pragma unroll
  for (int off = 32; off; off >>= 1) ri += __shfl_xor(ri, off, 64);
  if (lane == 0) red_s[w] = ri;

  const bool flag = (p >= 1e-7f);
  const unsigned long long mask = __ballot(flag);
  const int wc     = __popcll(mask);
  const int prefix = __popcll(mask & ((1ull << lane) - 1ull));
  if (lane == 0) warp_cnt[w] = wc;
  __syncthreads();

  if (t == 0) {
    const float tot_ri = red_s[0] + red_s[1] + red_s[2] + red_s[3];
    out_items[b] = (float)(int)tot_ri;
  }
  int off0 = 0;
  for (int i = 0; i < w; ++i) off0 += warp_cnt[i];
  const int nsel = warp_cnt[0] + warp_cnt[1] + warp_cnt[2] + warp_cnt[3];
  if (flag) {
    sel_idx[off0 + prefix] = myitem;
    sel_p[off0 + prefix]   = p;
  }
  __syncthreads();

  float acc = 0.f;
  for (int i = 0; i < nsel; ++i)
    acc += sel_p[i] * all_items[(size_t)sel_idx[i] * Dn + t];
  feat_out[(size_t)b * Dn + t] = acc;

  if (b == 0 && t < 2) out_scalars[t] = 0.f;
}

// ---------------------------------------------------------------------------
// Fallback main kernel (round-2, verified) for small ws_size.
// ---------------------------------------------------------------------------
__global__ __launch_bounds__(256) void main_fb(
    const int* __restrict__ need_replace,
    const int* __restrict__ user_sample_items,
    const float* __restrict__ all_items,
    float* __restrict__ out_items, float* __restrict__ feat_io,
    float* __restrict__ out_scalars) {
  __shared__ __align__(16) float f_s[Dn];
  __shared__ int   items_s[Sn];
  __shared__ float red_s[8];
  __shared__ int   sel_idx[Sn];
  __shared__ float sel_p[Sn];
  __shared__ int   warp_cnt[4];

  const int b = blockIdx.x, t = threadIdx.x;
  const int lane = t & 63, w = t >> 6;
  const int uid = need_replace[b * 2];
  items_s[t] = user_sample_items[(size_t)uid * Sn + t];
  f_s[t]     = feat_io[(size_t)b * Dn + t];
  __syncthreads();

  const float4 fr = *(const float4*)&f_s[lane * 4];
  const int base = w * 64;
  float4 e[8];
#pragma unroll
  for (int j = 0; j < 8; ++j)
    e[j] = *(const float4*)&all_items[(size_t)items_s[base + 8 * j] * Dn + lane * 4];
  float grp[8];
#pragma unroll
  for (int c = 0; c < 8; ++c) {
    float p[8];
#pragma unroll
    for (int j = 0; j < 8; ++j) {
      const float4 ev = e[j];
      p[j] = fmaf(fr.x, ev.x, fmaf(fr.y, ev.y, fmaf(fr.z, ev.z, fr.w * ev.w)));
      if (c < 7)
        e[j] = *(const float4*)&all_items[(size_t)items_s[base + (c + 1) + 8 * j] * Dn + lane * 4];
    }
    const float q0 = fold(p[0], p[4], 32, lane), q1 = fold(p[1], p[5], 32, lane);
    const float q2 = fold(p[2], p[6], 32, lane), q3 = fold(p[3], p[7], 32, lane);
    const float r0 = fold(q0, q2, 16, lane),     r1 = fold(q1, q3, 16, lane);
    grp[c] = fold(r0, r1, 8, lane);
  }
  const float s0 = fold(grp[0], grp[4], 4, lane), s1 = fold(grp[1], grp[5], 4, lane);
  const float s2 = fold(grp[2], grp[6], 4, lane), s3 = fold(grp[3], grp[7], 4, lane);
  const float t0 = fold(s0, s2, 2, lane),         t1 = fold(s1, s3, 2, lane);
  const float v  = fold(t0, t1, 1, lane);

  float m = v;
#pragma unroll
  for (int off = 32; off; off >>= 1) m = fmaxf(m, __shfl_xor(m, off, 64));
  if (lane == 0) red_s[w] = m;
  __syncthreads();
  m = fmaxf(fmaxf(red_s[0], red_s[1]), fmaxf(red_s[2], red_s[3]));
  const float e0 = expf(v - m);
  float ssum = e0;
#pragma unroll
  for (int off = 32; off; off >>= 1) ssum += __shfl_xor(ssum, off, 64);
  if (lane == 0) red_s[4 + w] = ssum;
  __syncthreads();
  const float tot = red_s[4] + red_s[5] + red_s[6] + red_s[7];
  const float p = e0 / tot;
  float ri = p * (float)items_s[t];
#pragma unroll
  for (int off = 32; off; off >>= 1) ri += __shfl_xor(ri, off, 64);
  if (lane == 0) red_s[w] = ri;
  const bool flag = (p >= 1e-7f);
  const unsigned long long mask = __ballot(flag);
  const int wc = __popcll(mask);
  const int prefix = __popcll(mask & ((1ull << lane) - 1ull));
  if (lane == 0) warp_cnt[w] = wc;
  __syncthreads();
  if (t == 0) {
    const float tot_ri = red_s[0] + red_s[1] + red_s[2] + red_s[3];
    out_items[b] = (float)(int)tot_ri;
  }
  int off0 = 0;
  for (int i = 0; i < w; ++i) off0 += warp_cnt[i];
  const int nsel = warp_cnt[0] + warp_cnt[1] + warp_cnt[2] + warp_cnt[3];
  if (flag) {
    sel_idx[off0 + prefix] = items_s[t];
    sel_p[off0 + prefix]   = p;
  }
  __syncthreads();
  float acc = 0.f;
  for (int i = 0; i < nsel; ++i)
    acc += sel_p[i] * all_items[(size_t)sel_idx[i] * Dn + t];
  feat_io[(size_t)b * Dn + t] = acc;
  if (b == 0 && t < 2) out_scalars[t] = 0.f;
}

extern "C" void kernel_launch(void* const* d_in, const int* in_sizes, int n_in,
                              void* d_out, int out_size, void* d_ws, size_t ws_size,
                              hipStream_t stream) {
  const int*   need_replace      = (const int*)d_in[0];
  const float* union_feature     = (const float*)d_in[1];
  const float* all_items         = (const float*)d_in[2];
  const float* privacy_settings  = (const float*)d_in[3];
  const int*   user_sample_items = (const int*)d_in[4];
  const float* W                 = (const float*)d_in[5];
  const float* bias              = (const float*)d_in[6];

  float* out       = (float*)d_out;
  float* out_items = out;
  float* feat_io   = out + Bn;
  float* out_scal  = out + Bn + (size_t)Bn * Dn;

  feat_v3<<<256, 256, 0, stream>>>(union_feature, privacy_settings, W, bias, feat_io);

  const size_t NEED = (size_t)(300000 + 512 + 2 * 1048576) * 4 + 1048576 * 4;  // ~13.8 MB
  if (ws_size >= NEED) {
    int* cnt       = (int*)d_ws;
    int* offsets   = cnt + 100000;
    int* cursor    = offsets + 100000;
    int* blocksum  = cursor + 100000;
    int* consumers = blocksum + 512;
    int* bsitems   = consumers + 1048576;
    float* scores  = (float*)(bsitems + 1048576);

    hipMemsetAsync(cnt, 0, NITEMS * sizeof(int), stream);
    gather_hist<<<Bn, 256, 0, stream>>>(need_replace, user_sample_items, bsitems, cnt);
    scan_a<<<NBLK_SCAN, 256, 0, stream>>>(cnt, offsets, blocksum);
    scan_b<<<1, 512, 0, stream>>>(blocksum, NBLK_SCAN);
    scan_c<<<NBLK_SCAN, 256, 0, stream>>>(offsets, cursor, blocksum);
    scatter_kernel<<<Bn, 256, 0, stream>>>(bsitems, cursor, consumers);
    score_kernel<<<(NITEMS + 3) / 4, 256, 0, stream>>>(all_items, feat_io, offsets,
                                                       cnt, consumers, scores);
    finish_kernel<<<Bn, 256, 0, stream>>>(bsitems, scores, all_items,
                                          out_items, feat_io, out_scal);
  } else {
    main_fb<<<Bn, 256, 0, stream>>>(need_replace, user_sample_items, all_items,
                                    out_items, feat_io, out_scal);
  }
}